// Round 8
// baseline (4115.022 us; speedup 1.0000x reference)
//
#include <hip/hip_runtime.h>

#define N_BOX 4096
#define NT    1024
#define KPT   4              // boxes per thread
#define NW    16             // waves
#define KTOP  16             // candidates per wave (4 per lane in sim)
#define MAXC  (NW * KTOP)    // 256
#define NEG_INF (-__builtin_huge_valf())

typedef unsigned long long u64;

// 64-lane max-reduce of a u64 key via DPP (VALU pipe); result broadcast via
// readlane(63). Proven bit-exact in round 7.
__device__ __forceinline__ u64 dpp_max_u64(u64 x) {
#define DPP_STEP(CTRL) { \
    int lo_ = __builtin_amdgcn_update_dpp(0, (int)(unsigned)x,         CTRL, 0xF, 0xF, true); \
    int hi_ = __builtin_amdgcn_update_dpp(0, (int)(unsigned)(x >> 32), CTRL, 0xF, 0xF, true); \
    u64 o_ = ((u64)(unsigned)hi_ << 32) | (unsigned)lo_; \
    x = (o_ > x) ? o_ : x; }
    DPP_STEP(0x111)   // row_shr:1
    DPP_STEP(0x112)   // row_shr:2
    DPP_STEP(0x114)   // row_shr:4
    DPP_STEP(0x118)   // row_shr:8
    DPP_STEP(0x142)   // row_bcast15
    DPP_STEP(0x143)   // row_bcast31
#undef DPP_STEP
    const int lo = __builtin_amdgcn_readlane((int)(unsigned)x, 63);
    const int hi = __builtin_amdgcn_readlane((int)(unsigned)(x >> 32), 63);
    return ((u64)(unsigned)hi << 32) | (unsigned)lo;
}

__device__ __forceinline__ float bcast_f32(float v, int ln) {
    return __int_as_float(__builtin_amdgcn_readlane(__float_as_int(v), ln));
}

__global__ __launch_bounds__(NT, 1) void soft_nms_kernel(
    const float* __restrict__ boxes,
    const float* __restrict__ scores,
    float* __restrict__ out)
{
    const int tid  = threadIdx.x;
    const int lane = tid & 63;
    const int wave = tid >> 6;

    __shared__ unsigned s_key[N_BOX];          // 16 KB (initial spatial sort)
    __shared__ u64      s_wtop[NW][KTOP + 1];  // per-wave top-16 keys + 17th (bound)
    __shared__ float    s_wgeom[NW][KTOP][5];  // geometry of per-wave top-16
    __shared__ int      s_cmt[MAXC];           // commit t -> (slot<<12)|spos
    __shared__ int      s_C;

    // ---- Morton keys of box centers (16x16 grid) | original index ----
    #pragma unroll
    for (int k = 0; k < KPT; ++k) {
        const int i = tid * KPT + k;
        const float4 b = reinterpret_cast<const float4*>(boxes)[i];
        const float cx = 0.5f * (b.x + b.z);
        const float cy = 0.5f * (b.y + b.w);
        int icx = (int)(cx * 0.016f); icx = icx < 0 ? 0 : (icx > 15 ? 15 : icx);
        int icy = (int)(cy * 0.016f); icy = icy < 0 ? 0 : (icy > 15 ? 15 : icy);
        unsigned m = 0;
        #pragma unroll
        for (int bb = 0; bb < 4; ++bb)
            m |= (((unsigned)(icx >> bb) & 1u) << (2*bb)) |
                 (((unsigned)(icy >> bb) & 1u) << (2*bb + 1));
        s_key[i] = (m << 12) | (unsigned)i;
    }
    __syncthreads();

    // ---- bitonic sort (ascending) of 4096 keys in LDS ----
    for (int kk = 2; kk <= N_BOX; kk <<= 1) {
        for (int j = kk >> 1; j > 0; j >>= 1) {
            #pragma unroll
            for (int t = 0; t < KPT; ++t) {
                const int e = tid + t * NT;
                const int p = e ^ j;
                if (p > e) {
                    const unsigned a = s_key[e], b = s_key[p];
                    const bool up = ((e & kk) == 0);
                    if ((a > b) == up) { s_key[e] = b; s_key[p] = a; }
                }
            }
            __syncthreads();
        }
    }

    // ---- gather boxes in spatially-sorted order; all state in registers ----
    float bx1[KPT], by1[KPT], bx2[KPT], by2[KPT], bar[KPT], cur[KPT], fin[KPT];
    unsigned klo[KPT];   // ((4095-oidx)<<13) | (spos+1)
    #pragma unroll
    for (int k = 0; k < KPT; ++k) {
        const int spos = tid * KPT + k;
        const int oi = (int)(s_key[spos] & 0xFFFu);
        const float4 b = reinterpret_cast<const float4*>(boxes)[oi];
        bx1[k] = b.x; by1[k] = b.y; bx2[k] = b.z; by2[k] = b.w;
        bar[k] = (b.z - b.x) * (b.w - b.y);
        cur[k] = scores[oi];
        fin[k] = 0.0f;
        klo[k] = ((unsigned)(4095 - oi) << 13) | (unsigned)(spos + 1);
    }

    // ---- thread bbox and wave bbox (register-resident) ----
    float tbx1 = bx1[0], tby1 = by1[0], tbx2 = bx2[0], tby2 = by2[0];
    #pragma unroll
    for (int k = 1; k < KPT; ++k) {
        tbx1 = fminf(tbx1, bx1[k]); tby1 = fminf(tby1, by1[k]);
        tbx2 = fmaxf(tbx2, bx2[k]); tby2 = fmaxf(tby2, by2[k]);
    }
    float wbx1 = tbx1, wby1 = tby1, wbx2 = tbx2, wby2 = tby2;
    #pragma unroll
    for (int off = 1; off < 64; off <<= 1) {
        wbx1 = fminf(wbx1, __shfl_xor(wbx1, off));
        wby1 = fminf(wby1, __shfl_xor(wby1, off));
        wbx2 = fmaxf(wbx2, __shfl_xor(wbx2, off));
        wby2 = fmaxf(wby2, __shfl_xor(wby2, off));
    }

    // ---- per-wave top-(K+1) rebuild: DPP pops (VALU pipe) ----
    auto rebuild = [&]() {
        u64 lk[KPT];
        #pragma unroll
        for (int k = 0; k < KPT; ++k)
            lk[k] = (cur[k] < 0.0f) ? 0ull
                  : (((u64)__float_as_uint(cur[k]) << 25) | (u64)klo[k]);
        for (int p = 0; p <= KTOP; ++p) {
            u64 m4 = lk[0];
            #pragma unroll
            for (int k = 1; k < KPT; ++k) m4 = lk[k] > m4 ? lk[k] : m4;
            const u64 m = dpp_max_u64(m4);
            if (lane == 0) s_wtop[wave][p] = m;
            if (p < KTOP && m != 0ull) {
                #pragma unroll
                for (int k = 0; k < KPT; ++k) {
                    if (lk[k] == m) {
                        lk[k] = 0ull;
                        s_wgeom[wave][p][0] = bx1[k];
                        s_wgeom[wave][p][1] = by1[k];
                        s_wgeom[wave][p][2] = bx2[k];
                        s_wgeom[wave][p][3] = by2[k];
                        s_wgeom[wave][p][4] = bar[k];
                    }
                }
            }
        }
    };

    rebuild();
    __syncthreads();

    // ---- batched selection rounds ----
    int remaining = N_BOX;
    int guard = 0;
    while (remaining > 0 && ++guard <= N_BOX) {
        // (1) wave 0: exact sequential selection over 256 candidates (4/lane)
        if (wave == 0) {
            const int cw = lane >> 2, cr = lane & 3;
            u64 ck0 = s_wtop[cw][cr];
            u64 ck1 = s_wtop[cw][4 + cr];
            u64 ck2 = s_wtop[cw][8 + cr];
            u64 ck3 = s_wtop[cw][12 + cr];
            float cx1[4], cy1[4], cx2[4], cy2[4], car[4];
            #pragma unroll
            for (int r = 0; r < 4; ++r) {
                cx1[r] = s_wgeom[cw][4*r + cr][0];
                cy1[r] = s_wgeom[cw][4*r + cr][1];
                cx2[r] = s_wgeom[cw][4*r + cr][2];
                cy2[r] = s_wgeom[cw][4*r + cr][3];
                car[r] = s_wgeom[cw][4*r + cr][4];
            }
            // threshold: max over waves of each wave's 17th-best key
            u64 tv = (lane < NW) ? s_wtop[lane][KTOP] : 0ull;
            const u64 T = dpp_max_u64(tv);
            int C = 0;
            while (C < MAXC) {
                u64 m4 = ck0 > ck1 ? ck0 : ck1;
                const u64 m23 = ck2 > ck3 ? ck2 : ck3;
                if (m23 > m4) m4 = m23;
                const u64 m = dpp_max_u64(m4);
                if (m <= T) break;          // selection no longer provably global
                // locate winner: lane + slot-rank (unique key => one match)
                int ln, r;
                u64 b = __ballot(ck0 == m);
                if (b) { r = 0; }
                else if ((b = __ballot(ck1 == m))) { r = 1; }
                else if ((b = __ballot(ck2 == m))) { r = 2; }
                else { b = __ballot(ck3 == m); r = 3; }
                ln = (int)__ffsll(b) - 1;
                const int cwin = (ln >> 2) * KTOP + 4 * r + (ln & 3);  // slot id
                if (lane == 0) s_cmt[C] = (cwin << 12) | (int)((m & 0x1FFFull) - 1);
                if (ck0 == m) ck0 = 0ull;
                if (ck1 == m) ck1 = 0ull;
                if (ck2 == m) ck2 = 0ull;
                if (ck3 == m) ck3 = 0ull;
                // selected geometry: wave-uniform 4-way select + readlane
                const float jx1 = bcast_f32(r == 0 ? cx1[0] : r == 1 ? cx1[1] : r == 2 ? cx1[2] : cx1[3], ln);
                const float jy1 = bcast_f32(r == 0 ? cy1[0] : r == 1 ? cy1[1] : r == 2 ? cy1[2] : cy1[3], ln);
                const float jx2 = bcast_f32(r == 0 ? cx2[0] : r == 1 ? cx2[1] : r == 2 ? cx2[2] : cx2[3], ln);
                const float jy2 = bcast_f32(r == 0 ? cy2[0] : r == 1 ? cy2[1] : r == 2 ? cy2[2] : cy2[3], ln);
                const float ja  = bcast_f32(r == 0 ? car[0] : r == 1 ? car[1] : r == 2 ? car[2] : car[3], ln);
#define DECAY_CK(CK, RR) \
                if (CK != 0ull) { \
                    const float xx1 = fmaxf(jx1, cx1[RR]), yy1 = fmaxf(jy1, cy1[RR]); \
                    const float xx2 = fminf(jx2, cx2[RR]), yy2 = fminf(jy2, cy2[RR]); \
                    const float w_ = fmaxf(xx2 - xx1, 0.0f), h_ = fmaxf(yy2 - yy1, 0.0f); \
                    const float inter = w_ * h_; \
                    if (inter > 0.0f) { \
                        const float iou = inter / (ja + car[RR] - inter); \
                        float s_ = __uint_as_float((unsigned)(CK >> 25)); \
                        s_ *= __expf(iou * iou * -2.0f); \
                        CK = ((u64)__float_as_uint(s_) << 25) | (CK & 0x1FFFFFFull); } }
                DECAY_CK(ck0, 0)
                DECAY_CK(ck1, 1)
                DECAY_CK(ck2, 2)
                DECAY_CK(ck3, 3)
#undef DECAY_CK
                ++C;
            }
            if (lane == 0) s_C = C;
        }
        __syncthreads();

        // (2) all waves apply committed decays in commit order
        const int C = s_C;
        bool wdirty = false;
        for (int t = 0; t < C; ++t) {
            const int rec  = s_cmt[t];
            const int slot = rec >> 12;
            const int sp   = rec & 0xFFF;
            const float jx1 = s_wgeom[slot >> 4][slot & 15][0];
            const float jy1 = s_wgeom[slot >> 4][slot & 15][1];
            const float jx2 = s_wgeom[slot >> 4][slot & 15][2];
            const float jy2 = s_wgeom[slot >> 4][slot & 15][3];
            const float ja  = s_wgeom[slot >> 4][slot & 15][4];
            // wave-level skip (uniform): no overlap => all weights exactly 1.0
            if (jx1 > wbx2 || jx2 < wbx1 || jy1 > wby2 || jy2 < wby1) continue;
            wdirty = true;
            const bool mine = (sp >> 2) == tid;
            if (!mine && (jx1 > tbx2 || jx2 < tbx1 || jy1 > tby2 || jy2 < tby1))
                continue;  // thread-level skip, bit-exact (all weights 1.0)
            #pragma unroll
            for (int k = 0; k < KPT; ++k) {
                if (mine && (sp & 3) == k) {
                    fin[k] = cur[k];        // freeze at selection time
                    cur[k] = NEG_INF;       // mark processed
                } else {
                    const float xx1 = fmaxf(jx1, bx1[k]);
                    const float yy1 = fmaxf(jy1, by1[k]);
                    const float xx2 = fminf(jx2, bx2[k]);
                    const float yy2 = fminf(jy2, by2[k]);
                    const float w = fmaxf(xx2 - xx1, 0.0f);
                    const float h = fmaxf(yy2 - yy1, 0.0f);
                    const float inter = w * h;
                    const float iou = inter / (ja + bar[k] - inter);
                    cur[k] *= __expf(iou * iou * -2.0f);   // -inf stays -inf
                }
            }
        }
        // all waves must finish READING s_wgeom before rebuild WRITES it
        __syncthreads();
        if (wdirty) rebuild();
        __syncthreads();
        remaining -= C;
    }

    // ---- scatter outputs back to original order ----
    #pragma unroll
    for (int k = 0; k < KPT; ++k) {
        const int oi = 4095 - (int)((klo[k] >> 13) & 0xFFFu);
        out[oi] = fin[k];
        out[N_BOX + oi] = (fin[k] > 0.05f) ? 1.0f : 0.0f;
    }
}

extern "C" void kernel_launch(void* const* d_in, const int* in_sizes, int n_in,
                              void* d_out, int out_size, void* d_ws, size_t ws_size,
                              hipStream_t stream) {
    const float* boxes  = (const float*)d_in[0];
    const float* scores = (const float*)d_in[1];
    float* out = (float*)d_out;
    soft_nms_kernel<<<1, NT, 0, stream>>>(boxes, scores, out);
}

// Round 9
// 2877.045 us; speedup vs baseline: 1.4303x; 1.4303x over previous
//
#include <hip/hip_runtime.h>

#define N_BOX 4096
#define NT    1024
#define KPT   4              // boxes per thread
#define NW    16             // waves
#define KTOP  8              // candidates per wave (2 per lane in sim)
#define MAXC  (NW * KTOP)    // 128
#define NEG_INF (-__builtin_huge_valf())

typedef unsigned long long u64;

// 64-lane max-reduce of a u64 key via DPP (VALU pipe); result broadcast via
// readlane(63). Proven bit-exact in round 7.
__device__ __forceinline__ u64 dpp_max_u64(u64 x) {
#define DPP_STEP(CTRL) { \
    int lo_ = __builtin_amdgcn_update_dpp(0, (int)(unsigned)x,         CTRL, 0xF, 0xF, true); \
    int hi_ = __builtin_amdgcn_update_dpp(0, (int)(unsigned)(x >> 32), CTRL, 0xF, 0xF, true); \
    u64 o_ = ((u64)(unsigned)hi_ << 32) | (unsigned)lo_; \
    x = (o_ > x) ? o_ : x; }
    DPP_STEP(0x111)   // row_shr:1
    DPP_STEP(0x112)   // row_shr:2
    DPP_STEP(0x114)   // row_shr:4
    DPP_STEP(0x118)   // row_shr:8
    DPP_STEP(0x142)   // row_bcast15
    DPP_STEP(0x143)   // row_bcast31
#undef DPP_STEP
    const int lo = __builtin_amdgcn_readlane((int)(unsigned)x, 63);
    const int hi = __builtin_amdgcn_readlane((int)(unsigned)(x >> 32), 63);
    return ((u64)(unsigned)hi << 32) | (unsigned)lo;
}

__device__ __forceinline__ float bcast_f32(float v, int ln) {
    return __int_as_float(__builtin_amdgcn_readlane(__float_as_int(v), ln));
}

__global__ __launch_bounds__(NT, 1) void soft_nms_kernel(
    const float* __restrict__ boxes,
    const float* __restrict__ scores,
    float* __restrict__ out)
{
    const int tid  = threadIdx.x;
    const int lane = tid & 63;
    const int wave = tid >> 6;

    __shared__ unsigned s_key[N_BOX];             // 16 KB (initial spatial sort)
    __shared__ u64      s_wtop[2][NW][KTOP + 1];  // ping-pong top-8 keys + 9th
    __shared__ float    s_wgeom[2][NW][KTOP][5];  // ping-pong geometry
    __shared__ int      s_cmt[MAXC];              // commit t -> (slot<<12)|spos
    __shared__ int      s_wlist[NW][MAXC];        // per-wave commit index list
    __shared__ int      s_C;

    // ---- Morton keys of box centers (16x16 grid) | original index ----
    #pragma unroll
    for (int k = 0; k < KPT; ++k) {
        const int i = tid * KPT + k;
        const float4 b = reinterpret_cast<const float4*>(boxes)[i];
        const float cx = 0.5f * (b.x + b.z);
        const float cy = 0.5f * (b.y + b.w);
        int icx = (int)(cx * 0.016f); icx = icx < 0 ? 0 : (icx > 15 ? 15 : icx);
        int icy = (int)(cy * 0.016f); icy = icy < 0 ? 0 : (icy > 15 ? 15 : icy);
        unsigned m = 0;
        #pragma unroll
        for (int bb = 0; bb < 4; ++bb)
            m |= (((unsigned)(icx >> bb) & 1u) << (2*bb)) |
                 (((unsigned)(icy >> bb) & 1u) << (2*bb + 1));
        s_key[i] = (m << 12) | (unsigned)i;
    }
    __syncthreads();

    // ---- bitonic sort (ascending) of 4096 keys in LDS ----
    for (int kk = 2; kk <= N_BOX; kk <<= 1) {
        for (int j = kk >> 1; j > 0; j >>= 1) {
            #pragma unroll
            for (int t = 0; t < KPT; ++t) {
                const int e = tid + t * NT;
                const int p = e ^ j;
                if (p > e) {
                    const unsigned a = s_key[e], b = s_key[p];
                    const bool up = ((e & kk) == 0);
                    if ((a > b) == up) { s_key[e] = b; s_key[p] = a; }
                }
            }
            __syncthreads();
        }
    }

    // ---- gather boxes in spatially-sorted order; all state in registers ----
    float bx1[KPT], by1[KPT], bx2[KPT], by2[KPT], bar[KPT], cur[KPT], fin[KPT];
    unsigned klo[KPT];   // ((4095-oidx)<<13) | (spos+1)
    #pragma unroll
    for (int k = 0; k < KPT; ++k) {
        const int spos = tid * KPT + k;
        const int oi = (int)(s_key[spos] & 0xFFFu);
        const float4 b = reinterpret_cast<const float4*>(boxes)[oi];
        bx1[k] = b.x; by1[k] = b.y; bx2[k] = b.z; by2[k] = b.w;
        bar[k] = (b.z - b.x) * (b.w - b.y);
        cur[k] = scores[oi];
        fin[k] = 0.0f;
        klo[k] = ((unsigned)(4095 - oi) << 13) | (unsigned)(spos + 1);
    }

    // ---- thread bbox and wave bbox (register-resident) ----
    float tbx1 = bx1[0], tby1 = by1[0], tbx2 = bx2[0], tby2 = by2[0];
    #pragma unroll
    for (int k = 1; k < KPT; ++k) {
        tbx1 = fminf(tbx1, bx1[k]); tby1 = fminf(tby1, by1[k]);
        tbx2 = fmaxf(tbx2, bx2[k]); tby2 = fmaxf(tby2, by2[k]);
    }
    float wbx1 = tbx1, wby1 = tby1, wbx2 = tbx2, wby2 = tby2;
    #pragma unroll
    for (int off = 1; off < 64; off <<= 1) {
        wbx1 = fminf(wbx1, __shfl_xor(wbx1, off));
        wby1 = fminf(wby1, __shfl_xor(wby1, off));
        wbx2 = fmaxf(wbx2, __shfl_xor(wbx2, off));
        wby2 = fmaxf(wby2, __shfl_xor(wby2, off));
    }

    // ---- per-wave top-(K+1) rebuild into generation G: DPP pops ----
    auto rebuild = [&](int G) {
        u64 lk[KPT];
        #pragma unroll
        for (int k = 0; k < KPT; ++k)
            lk[k] = (cur[k] < 0.0f) ? 0ull
                  : (((u64)__float_as_uint(cur[k]) << 25) | (u64)klo[k]);
        #pragma unroll
        for (int p = 0; p <= KTOP; ++p) {
            u64 m4 = lk[0];
            #pragma unroll
            for (int k = 1; k < KPT; ++k) m4 = lk[k] > m4 ? lk[k] : m4;
            const u64 m = dpp_max_u64(m4);
            if (lane == 0) s_wtop[G][wave][p] = m;
            if (p < KTOP && m != 0ull) {
                #pragma unroll
                for (int k = 0; k < KPT; ++k) {
                    if (lk[k] == m) {
                        lk[k] = 0ull;
                        s_wgeom[G][wave][p][0] = bx1[k];
                        s_wgeom[G][wave][p][1] = by1[k];
                        s_wgeom[G][wave][p][2] = bx2[k];
                        s_wgeom[G][wave][p][3] = by2[k];
                        s_wgeom[G][wave][p][4] = bar[k];
                    }
                }
            }
        }
    };

    rebuild(0);
    int g = 0;
    __syncthreads();   // barrier A: generation g fully written

    // ---- batched selection rounds (2 barriers per round) ----
    int remaining = N_BOX;
    int guard = 0;
    while (remaining > 0 && ++guard <= N_BOX) {
        // (1) wave 0: exact sequential selection over 128 candidates (gen g)
        if (wave == 0) {
            const int cw = lane >> 2, cr = lane & 3;
            u64 ck0 = s_wtop[g][cw][cr];
            u64 ck1 = s_wtop[g][cw][4 + cr];
            const float c0x1 = s_wgeom[g][cw][cr][0],   c0y1 = s_wgeom[g][cw][cr][1];
            const float c0x2 = s_wgeom[g][cw][cr][2],   c0y2 = s_wgeom[g][cw][cr][3];
            const float c0ar = s_wgeom[g][cw][cr][4];
            const float c1x1 = s_wgeom[g][cw][4+cr][0], c1y1 = s_wgeom[g][cw][4+cr][1];
            const float c1x2 = s_wgeom[g][cw][4+cr][2], c1y2 = s_wgeom[g][cw][4+cr][3];
            const float c1ar = s_wgeom[g][cw][4+cr][4];
            // threshold: max over waves of each wave's 9th-best key
            u64 tv = (lane < NW) ? s_wtop[g][lane][KTOP] : 0ull;
            const u64 T = dpp_max_u64(tv);
            int C = 0;
            while (C < MAXC) {
                u64 m4 = ck0 > ck1 ? ck0 : ck1;
                const u64 m = dpp_max_u64(m4);
                if (m <= T) break;          // selection no longer provably global
                const u64 b0 = __ballot(ck0 == m);
                int ln; bool r1;
                if (b0) { ln = (int)__ffsll(b0) - 1; r1 = false; }
                else    { ln = (int)__ffsll(__ballot(ck1 == m)) - 1; r1 = true; }
                const int slot = (ln >> 2) * KTOP + (r1 ? 4 : 0) + (ln & 3);
                if (lane == 0) s_cmt[C] = (slot << 12) | (int)((m & 0x1FFFull) - 1);
                if (ck0 == m) ck0 = 0ull;
                if (ck1 == m) ck1 = 0ull;
                // selected geometry: readlane from owner lane's registers
                const float jx1 = bcast_f32(r1 ? c1x1 : c0x1, ln);
                const float jy1 = bcast_f32(r1 ? c1y1 : c0y1, ln);
                const float jx2 = bcast_f32(r1 ? c1x2 : c0x2, ln);
                const float jy2 = bcast_f32(r1 ? c1y2 : c0y2, ln);
                const float ja  = bcast_f32(r1 ? c1ar : c0ar, ln);
#define DECAY_CK(CK, CX1, CY1, CX2, CY2, CAR) \
                if (CK != 0ull) { \
                    const float xx1 = fmaxf(jx1, CX1), yy1 = fmaxf(jy1, CY1); \
                    const float xx2 = fminf(jx2, CX2), yy2 = fminf(jy2, CY2); \
                    const float w_ = fmaxf(xx2 - xx1, 0.0f), h_ = fmaxf(yy2 - yy1, 0.0f); \
                    const float inter = w_ * h_; \
                    if (inter > 0.0f) { \
                        const float iou = inter / (ja + CAR - inter); \
                        float s_ = __uint_as_float((unsigned)(CK >> 25)); \
                        s_ *= __expf(iou * iou * -2.0f); \
                        CK = ((u64)__float_as_uint(s_) << 25) | (CK & 0x1FFFFFFull); } }
                DECAY_CK(ck0, c0x1, c0y1, c0x2, c0y2, c0ar)
                DECAY_CK(ck1, c1x1, c1y1, c1x2, c1y2, c1ar)
#undef DECAY_CK
                ++C;
            }
            if (lane == 0) s_C = C;
        }
        __syncthreads();   // barrier B: s_cmt/s_C visible

        const int C = s_C;

        // (2a) build this wave's compacted commit list (reads gen g)
        int myn = 0;
        for (int t0 = 0; t0 < C; t0 += 64) {
            const int t = t0 + lane;
            bool pred = false;
            if (t < C) {
                const int slot = s_cmt[t] >> 12;
                const float jx1 = s_wgeom[g][slot >> 3][slot & 7][0];
                const float jy1 = s_wgeom[g][slot >> 3][slot & 7][1];
                const float jx2 = s_wgeom[g][slot >> 3][slot & 7][2];
                const float jy2 = s_wgeom[g][slot >> 3][slot & 7][3];
                pred = !(jx1 > wbx2 || jx2 < wbx1 || jy1 > wby2 || jy2 < wby1);
            }
            const u64 mask = __ballot(pred);
            if (pred) {
                const int pos = myn + (int)__popcll(mask & ((1ull << lane) - 1ull));
                s_wlist[wave][pos] = t;
            }
            myn += (int)__popcll(mask);
        }

        // (2b) apply this wave's commits in commit order (reads gen g)
        for (int n = 0; n < myn; ++n) {
            const int rec  = s_cmt[s_wlist[wave][n]];
            const int slot = rec >> 12;
            const int sp   = rec & 0xFFF;
            const float jx1 = s_wgeom[g][slot >> 3][slot & 7][0];
            const float jy1 = s_wgeom[g][slot >> 3][slot & 7][1];
            const float jx2 = s_wgeom[g][slot >> 3][slot & 7][2];
            const float jy2 = s_wgeom[g][slot >> 3][slot & 7][3];
            const float ja  = s_wgeom[g][slot >> 3][slot & 7][4];
            const bool mine = (sp >> 2) == tid;
            if (!mine && (jx1 > tbx2 || jx2 < tbx1 || jy1 > tby2 || jy2 < tby1))
                continue;  // thread-level skip, bit-exact (all weights 1.0)
            #pragma unroll
            for (int k = 0; k < KPT; ++k) {
                if (mine && (sp & 3) == k) {
                    fin[k] = cur[k];        // freeze at selection time
                    cur[k] = NEG_INF;       // mark processed
                } else {
                    const float xx1 = fmaxf(jx1, bx1[k]);
                    const float yy1 = fmaxf(jy1, by1[k]);
                    const float xx2 = fminf(jx2, bx2[k]);
                    const float yy2 = fminf(jy2, by2[k]);
                    const float w = fmaxf(xx2 - xx1, 0.0f);
                    const float h = fmaxf(yy2 - yy1, 0.0f);
                    const float inter = w * h;
                    const float iou = inter / (ja + bar[k] - inter);
                    cur[k] *= __expf(iou * iou * -2.0f);   // -inf stays -inf
                }
            }
        }

        // (2c) write generation g^1: rebuild if touched, else lane-copy
        if (myn > 0) {
            rebuild(g ^ 1);
        } else {
            if (lane <= KTOP) s_wtop[g ^ 1][wave][lane] = s_wtop[g][wave][lane];
            if (lane < KTOP * 5)
                ((float*)s_wgeom[g ^ 1][wave])[lane] =
                    ((const float*)s_wgeom[g][wave])[lane];
        }
        g ^= 1;
        remaining -= C;
        __syncthreads();   // barrier A of next round: gen g fully written
    }

    // ---- scatter outputs back to original order ----
    #pragma unroll
    for (int k = 0; k < KPT; ++k) {
        const int oi = 4095 - (int)((klo[k] >> 13) & 0xFFFu);
        out[oi] = fin[k];
        out[N_BOX + oi] = (fin[k] > 0.05f) ? 1.0f : 0.0f;
    }
}

extern "C" void kernel_launch(void* const* d_in, const int* in_sizes, int n_in,
                              void* d_out, int out_size, void* d_ws, size_t ws_size,
                              hipStream_t stream) {
    const float* boxes  = (const float*)d_in[0];
    const float* scores = (const float*)d_in[1];
    float* out = (float*)d_out;
    soft_nms_kernel<<<1, NT, 0, stream>>>(boxes, scores, out);
}